// Round 7
// baseline (1092.201 us; speedup 1.0000x reference)
//
#include <hip/hip_runtime.h>
#include <cstdint>
#include <cstddef>

#define NSAMP 4096
#define KDIM  512
#define TOT   49536   // 3 * (128*128 + 128)
#define NUMN  387     // TOT / 128
#define LCHUNK 16512  // 128 + 128*128, per-layer temp stride

typedef __attribute__((ext_vector_type(8))) __bf16 bf16x8;
typedef __attribute__((ext_vector_type(4))) __bf16 bf16x4;
typedef __attribute__((ext_vector_type(4))) float  f32x4;

#define AS1 __attribute__((address_space(1)))
#define AS3 __attribute__((address_space(3)))

// ---------------------------------------------------------------------------
// fp32 -> bf16 cast, 4 elements per thread (float4 read, 8B write)
// ---------------------------------------------------------------------------
__global__ void cast_bf16(const float* __restrict__ in, __bf16* __restrict__ out, int n4) {
    int i = blockIdx.x * blockDim.x + threadIdx.x;
    int stride = gridDim.x * blockDim.x;
    for (; i < n4; i += stride) {
        float4 v = ((const float4*)in)[i];
        bf16x4 o = { (__bf16)v.x, (__bf16)v.y, (__bf16)v.z, (__bf16)v.w };
        ((bf16x4*)out)[i] = o;
    }
}

// ---------------------------------------------------------------------------
// Hypernetwork GEMM: C[m][n] = sum_k A[m][k]*B[n][k] + bias[n]
// R12: PERSISTENT-A blocks. Evidence: R11 cut staged L2 bytes 4x and got
// SLOWER (latency-bound, 1 block/CU); R4 at 9.3 TB/s staging = 27% of L2
// peak (NOT BW-bound); R10 died of 1 wave/SIMD. Diagnosis: per-kt
// stage->drain serialization + A re-staged by every n-block. Fix:
//  - grid = 256 blocks exactly (1/CU, one round, no restarts)
//  - 512 threads = 8 waves = 2 waves/SIMD (R10's flaw fixed)
//  - A panel (128x512 = 128KB) resident in LDS, staged ONCE; one barrier
//    in the whole kernel
//  - each block sweeps ~24 n-tiles; B streams global->VGPR (R10's verified
//    fragment pattern: 16 full cache lines per wave-instr), 4-slot register
//    ring, prefetch distance 2 kt; ZERO barriers / vmcnt(0) drains in the
//    sweep — compiler's per-register counted waits do the pipelining
//  - A ds_reads use the proven xor-granule swizzle (2-way = free)
// ---------------------------------------------------------------------------
__global__ __launch_bounds__(512, 2) void hyper_gemm(
    const __bf16* __restrict__ A, const __bf16* __restrict__ B,
    const float* __restrict__ bias, __bf16* __restrict__ C)
{
    __shared__ __bf16 As[128 * KDIM];   // 128 KB resident A panel

    const int tid  = threadIdx.x;
    const int lane = tid & 63;
    const int quad = lane >> 4;       // 0..3
    const int r16  = lane & 15;       // 0..15
    const int wv   = tid >> 6;        // 0..7
    const int wm   = wv >> 2;         // 0..1 -> 64 output rows each
    const int wn   = wv & 3;          // 0..3 -> 32 output cols each

    const int m0 = blockIdx.y * 128;  // chunk-local row base

    // ---- n-tile range for this block: split 387 tiles over gridDim.x groups
    const int G   = gridDim.x;
    const int q   = NUMN / G, rem = NUMN % G;
    const int g   = blockIdx.x;
    const int nt0 = g * q + (g < rem ? g : rem);
    const int ntE = nt0 + q + (g < rem ? 1 : 0);

    // ---- stage A panel once: 16 passes x 8KB. Pass p: row = p*8 + wv,
    // granule g = lane (64 x 16B per 1KB row). xor-swizzle per 64-elem
    // k-block with key row&7 == wv (hoisted). LDS linear (lane-contiguous).
    {
        const __bf16* aBase = A + (size_t)(m0 + wv) * KDIM
                            + (lane >> 3) * 64 + ((lane & 7) ^ wv) * 8;
#pragma unroll
        for (int p = 0; p < 16; ++p) {
            __builtin_amdgcn_global_load_lds((AS1 void*)(aBase + (size_t)p * 8 * KDIM),
                (AS3 void*)(As + (p * 512 + tid) * 8), 16, 0, 0);
        }
    }

    // ---- B fragment base: lane covers C-col n = nt*128 + wn*32 + j*16 + r16,
    // k-granule quad*8 + kk*32 within kt*64. 4 lanes/row consume one full
    // 64B line -> 16 lines per wave-instr, perfectly coalesced.
    const __bf16* gB = B + (size_t)(nt0 * 128 + wn * 32 + r16) * KDIM + quad * 8;

    bf16x8 bb[4][2][2];   // [slot][j][kk] ring, prefetch distance 2
#define LOADB(slot, ptr, ktv) { _Pragma("unroll") for (int j = 0; j < 2; ++j) \
    _Pragma("unroll") for (int kk = 0; kk < 2; ++kk) \
        bb[slot][j][kk] = *(const bf16x8*)((ptr) + (size_t)j * 16 * KDIM + (ktv) * 64 + kk * 32); }

    const int rsw = r16 & 7;          // A read-phase swizzle key
    const int aRow = (wm * 64 + r16) * KDIM;

    f32x4 acc[4][2] = {};

    LOADB(0, gB, 0);
    LOADB(1, gB, 1);
    __syncthreads();   // the kernel's ONE barrier: A panel landed

    for (int nt = nt0; nt < ntE; ++nt) {
        const __bf16* gBn = gB + ((nt + 1 < ntE) ? (size_t)128 * KDIM : 0);

#pragma unroll
        for (int kt = 0; kt < 8; ++kt) {
            // prefetch kt+2 (crossing into next n-tile at kt>=6)
            if (kt < 6) { LOADB((kt + 2) & 3, gB, kt + 2); }
            else        { LOADB((kt + 2) & 3, gBn, kt - 6); }

            bf16x8 af[4][2];
#pragma unroll
            for (int i = 0; i < 4; ++i)
#pragma unroll
                for (int kk = 0; kk < 2; ++kk)
                    af[i][kk] = *(const bf16x8*)(As + aRow + i * 16 * KDIM + kt * 64
                                                 + (((kk * 4 + quad) ^ rsw) * 8));
#pragma unroll
            for (int i = 0; i < 4; ++i)
#pragma unroll
                for (int j = 0; j < 2; ++j) {
                    acc[i][j] = __builtin_amdgcn_mfma_f32_16x16x32_bf16(
                        af[i][0], bb[kt & 3][j][0], acc[i][j], 0, 0, 0);
                    acc[i][j] = __builtin_amdgcn_mfma_f32_16x16x32_bf16(
                        af[i][1], bb[kt & 3][j][1], acc[i][j], 0, 0, 0);
                }
        }

        // ---- per-n-tile epilogue: C/D layout col=lane&15, row=(lane>>4)*4+reg
#pragma unroll
        for (int j = 0; j < 2; ++j) {
            int n = nt * 128 + wn * 32 + j * 16 + r16;
            float bv = bias[n];
#pragma unroll
            for (int i = 0; i < 4; ++i) {
                int mbase = m0 + wm * 64 + i * 16 + quad * 4;
#pragma unroll
                for (int rr = 0; rr < 4; ++rr) {
                    C[(size_t)(mbase + rr) * TOT + n] = (__bf16)(acc[i][j][rr] + bv);
                }
                acc[i][j] = (f32x4){0.f, 0.f, 0.f, 0.f};
            }
        }
        gB = gBn;
    }
#undef LOADB
}

// ---------------------------------------------------------------------------
// Stage 2: per-sample 3-layer MLP with hypernetwork weights from temp chunk.
// Unchanged (T14 cross-layer weight prefetch; bias hoisted). TOT row stride.
// ---------------------------------------------------------------------------
__global__ __launch_bounds__(256) void mlp_kernel(
    const float* __restrict__ x, const __bf16* __restrict__ temp,
    float* __restrict__ out, int samp0)
{
    const int n   = samp0 + blockIdx.x;   // global sample index
    const int tid = threadIdx.x;
    const int wv  = tid >> 6;             // 0..3
    const int l   = tid & 63;
    const int pg  = l >> 4;               // 0..3
    const int qg  = l & 15;               // 0..15

    __shared__ float h[128];
    __shared__ float partial[4][128];

    if (tid < 64) ((float2*)h)[tid] = ((const float2*)(x + (size_t)n * 128))[tid];

    const __bf16* row = temp + (size_t)blockIdx.x * TOT;   // chunk-local temp row

    // prefetch layer-0 weights (independent of h)
    bf16x8 w[8];
#pragma unroll
    for (int i = 0; i < 8; ++i)
        w[i] = *(const bf16x8*)(row + 128 + (size_t)(wv * 32 + i * 4 + pg) * 128 + qg * 8);

    int cum = 0;
#pragma unroll
    for (int layer = 0; layer < 3; ++layer) {
        bf16x8 wn2[8];
        if (layer < 2) {
#pragma unroll
            for (int i = 0; i < 8; ++i)
                wn2[i] = *(const bf16x8*)(row + cum + LCHUNK + 128
                        + (size_t)(wv * 32 + i * 4 + pg) * 128 + qg * 8);
        }
        float bv = 0.f;
        if (tid < 128) bv = (float)row[cum + tid];

        float acc[8] = {0, 0, 0, 0, 0, 0, 0, 0};
        __syncthreads();   // h ready
#pragma unroll
        for (int i = 0; i < 8; ++i) {
            float hp = h[wv * 32 + i * 4 + pg];
#pragma unroll
            for (int j = 0; j < 8; ++j) acc[j] += (float)w[i][j] * hp;
        }
#pragma unroll
        for (int j = 0; j < 8; ++j) {
            acc[j] += __shfl_xor(acc[j], 16);
            acc[j] += __shfl_xor(acc[j], 32);
        }
        if (pg == 0) {
#pragma unroll
            for (int j = 0; j < 8; ++j) partial[wv][qg * 8 + j] = acc[j];
        }
        __syncthreads();   // partials ready; everyone done reading h
        if (tid < 128) {
            float v = partial[0][tid] + partial[1][tid] + partial[2][tid] + partial[3][tid]
                    + bv;
            if (layer < 2) v = fmaxf(v, 0.f);
            h[tid] = v;
        }
        if (layer < 2) {
#pragma unroll
            for (int i = 0; i < 8; ++i) w[i] = wn2[i];
        }
        cum += LCHUNK;
    }
    __syncthreads();
    if (tid < 64) ((float2*)(out + (size_t)n * 128))[tid] = ((const float2*)h)[tid];
}

// ---------------------------------------------------------------------------
extern "C" void kernel_launch(void* const* d_in, const int* in_sizes, int n_in,
                              void* d_out, int out_size, void* d_ws, size_t ws_size,
                              hipStream_t stream) {
    const float* int_x = (const float*)d_in[0];  // 4096 x 512
    const float* x     = (const float*)d_in[1];  // 4096 x 128
    const float* W     = (const float*)d_in[2];  // 49536 x 512
    const float* b     = (const float*)d_in[3];  // 49536
    float* out = (float*)d_out;                  // 4096 x 128

    // workspace layout (bf16): A_bf (4 MB) | W_bf (50.7 MB) | temp chunk
    char* ws = (char*)d_ws;
    __bf16* A_bf = (__bf16*)ws;
    size_t offA = (size_t)NSAMP * KDIM * 2;
    __bf16* W_bf = (__bf16*)(ws + offA);
    size_t offW = offA + (size_t)TOT * KDIM * 2;
    __bf16* temp = (__bf16*)(ws + offW);

    // Adaptive chunk: largest of {4096..128} whose temp fits remaining ws.
    // Deterministic given ws_size -> identical work every call (capture-safe).
    size_t remain = (ws_size > offW) ? (ws_size - offW) : 0;
    int chunk = 128;
    for (int c = 4096; c >= 128; c >>= 1) {
        if ((size_t)c * TOT * 2 <= remain) { chunk = c; break; }
    }

    int nA4 = NSAMP * KDIM / 4;
    cast_bf16<<<(nA4 + 255) / 256, 256, 0, stream>>>(int_x, A_bf, nA4);
    int nW4 = TOT * KDIM / 4;
    cast_bf16<<<(nW4 + 255) / 256, 256, 0, stream>>>(W, W_bf, nW4);

    for (int samp0 = 0; samp0 < NSAMP; samp0 += chunk) {
        int num_m = chunk / 128;
        int G = 256 / num_m; if (G < 1) G = 1;      // ~256 blocks = 1/CU
        dim3 grid(G, num_m);
        hyper_gemm<<<grid, 512, 0, stream>>>(A_bf + (size_t)samp0 * KDIM, W_bf, b, temp);
        mlp_kernel<<<chunk, 256, 0, stream>>>(x, temp, out, samp0);
    }
}

// Round 8
// 484.234 us; speedup vs baseline: 2.2555x; 2.2555x over previous
//
#include <hip/hip_runtime.h>
#include <cstdint>
#include <cstddef>

#define NSAMP 4096
#define KDIM  512
#define TOT   49536   // 3 * (128*128 + 128)
#define NUMN  387     // TOT / 128
#define BK    64
#define LCHUNK 16512  // 128 + 128*128, per-layer temp stride

typedef __attribute__((ext_vector_type(8))) __bf16 bf16x8;
typedef __attribute__((ext_vector_type(4))) __bf16 bf16x4;
typedef __attribute__((ext_vector_type(4))) float  f32x4;

#define AS1 __attribute__((address_space(1)))
#define AS3 __attribute__((address_space(3)))

// ---------------------------------------------------------------------------
// fp32 -> bf16 cast, 4 elements per thread (float4 read, 8B write)
// ---------------------------------------------------------------------------
__global__ void cast_bf16(const float* __restrict__ in, __bf16* __restrict__ out, int n4) {
    int i = blockIdx.x * blockDim.x + threadIdx.x;
    int stride = gridDim.x * blockDim.x;
    for (; i < n4; i += stride) {
        float4 v = ((const float4*)in)[i];
        bf16x4 o = { (__bf16)v.x, (__bf16)v.y, (__bf16)v.z, (__bf16)v.w };
        ((bf16x4*)out)[i] = o;
    }
}

// ---------------------------------------------------------------------------
// Hypernetwork GEMM: C[m][n] = sum_k A[m][k]*B[n][k] + bias[n]
// R13: BM=256 x BN=128 tile, 4 waves each owning 128x64, single-buffered
// 48KB LDS, R1's exact 2-barrier loop. Rationale from R1/R4/R10/R11/R12:
//  - R12 (direct-B->VGPR) exploded FETCH 77->678MB: B MUST flow through LDS
//    once per block (L2 can't dedupe 32 private sweeps/XCD).
//  - R4 not HBM/L2-BW/conflict-bound; consistent model = LDS-port +
//    per-block overhead. R13 cuts LDS reads/MFMA 0.5->0.375, halves staged
//    bytes per output (48KB/kt for 2x output), halves block count
//    (6192->3096).
//  - single-buffer keeps LDS at 48KB so 2 blocks/CU stay co-resident
//    (launch_bounds(256,2)); R1==R4 proved dbuf buys nothing here, and
//    co-resident blocks are what cover the stage drains (R11's fatal loss).
// ---------------------------------------------------------------------------
__global__ __launch_bounds__(256, 2) void hyper_gemm(
    const __bf16* __restrict__ A, const __bf16* __restrict__ B,
    const float* __restrict__ bias, __bf16* __restrict__ C)
{
    __shared__ __bf16 As[256 * BK];   // 32 KB
    __shared__ __bf16 Bs[128 * BK];   // 16 KB

    const int tid   = threadIdx.x;
    const int lane  = tid & 63;
    const int quad  = lane >> 4;      // 0..3
    const int r16   = lane & 15;      // 0..15
    const int wv    = tid >> 6;       // 0..3
    const int wm    = wv >> 1;        // 0..1 -> 128 output rows each
    const int wn    = wv & 1;         // 0..1 -> 64 output cols each

    // ---- XCD-congruent swizzle: same-n_t blocks -> same XCD, adjacent ids
    const int num_m = gridDim.y;                    // chunk/256
    const int id    = blockIdx.y * NUMN + blockIdx.x;
    const int gsz   = 8 * num_m;                    // supergroup block count
    const int s     = id / gsz;
    const int r     = id % gsz;
    const int base  = s * 8;
    int w = NUMN - base; if (w > 8) w = 8;          // partial last group (387%8=3)
    const int n_t = base + r % w;
    const int m_t = r / w;

    const int m0 = m_t * 256;   // chunk-local row
    const int n0 = n_t * 128;

    f32x4 acc[8][4] = {};

    // ---- per-thread staging geometry (k-invariant, hoisted)
    // A: 8 granule-chunks (2048 x 16B), B: 4 (1024 x 16B). idx=c*256+tid;
    // row=idx>>3; granule=idx&7 xor-swizzled by row&7; LDS stays linear.
    const __bf16* gAp[8];
    const __bf16* gBp[4];
    int ldsAOff[8], ldsBOff[4];
#pragma unroll
    for (int c = 0; c < 8; ++c) {
        int idx  = c * 256 + tid;           // 0..2047
        int row  = idx >> 3;                // 0..255
        int gsrc = (idx & 7) ^ (row & 7);
        gAp[c] = A + (size_t)(m0 + row) * KDIM + gsrc * 8;
        ldsAOff[c] = idx * 8;
    }
#pragma unroll
    for (int c = 0; c < 4; ++c) {
        int idx  = c * 256 + tid;           // 0..1023
        int row  = idx >> 3;                // 0..127
        int gsrc = (idx & 7) ^ (row & 7);
        gBp[c] = B + (size_t)(n0 + row) * KDIM + gsrc * 8;
        ldsBOff[c] = idx * 8;
    }

    const int rsw = r16 & 7;          // read-phase swizzle key

    for (int kt = 0; kt < KDIM / BK; ++kt) {
        const int k0 = kt * BK;
#pragma unroll
        for (int c = 0; c < 8; ++c)
            __builtin_amdgcn_global_load_lds((AS1 void*)(gAp[c] + k0),
                (AS3 void*)(As + ldsAOff[c]), 16, 0, 0);
#pragma unroll
        for (int c = 0; c < 4; ++c)
            __builtin_amdgcn_global_load_lds((AS1 void*)(gBp[c] + k0),
                (AS3 void*)(Bs + ldsBOff[c]), 16, 0, 0);
        __syncthreads();

        // --- two sub-k MFMA passes (kk = 0,1), 32 MFMA each
#pragma unroll
        for (int kk = 0; kk < 2; ++kk) {
            bf16x8 af[8], bf[4];
#pragma unroll
            for (int i = 0; i < 8; ++i) {
                int rr = wm * 128 + i * 16 + r16;
                af[i] = *(const bf16x8*)(As + rr * BK + (((kk * 4 + quad) ^ rsw) * 8));
            }
#pragma unroll
            for (int j = 0; j < 4; ++j) {
                int rr = wn * 64 + j * 16 + r16;
                bf[j] = *(const bf16x8*)(Bs + rr * BK + (((kk * 4 + quad) ^ rsw) * 8));
            }
#pragma unroll
            for (int i = 0; i < 8; ++i)
#pragma unroll
                for (int j = 0; j < 4; ++j)
                    acc[i][j] = __builtin_amdgcn_mfma_f32_16x16x32_bf16(af[i], bf[j], acc[i][j], 0, 0, 0);
        }
        __syncthreads();
    }

    // --- epilogue: C/D layout col=lane&15, row=(lane>>4)*4+reg. Fuse bias,
    // cast bf16, plain stores.
#pragma unroll
    for (int j = 0; j < 4; ++j) {
        int n = n0 + wn * 64 + j * 16 + r16;
        float bb = bias[n];
#pragma unroll
        for (int i = 0; i < 8; ++i) {
            int mbase = m0 + wm * 128 + i * 16 + quad * 4;
#pragma unroll
            for (int rr = 0; rr < 4; ++rr) {
                C[(size_t)(mbase + rr) * TOT + n] = (__bf16)(acc[i][j][rr] + bb);
            }
        }
    }
}

// ---------------------------------------------------------------------------
// Stage 2: per-sample 3-layer MLP with hypernetwork weights from temp chunk.
// Unchanged (T14 cross-layer weight prefetch; bias hoisted). TOT row stride.
// ---------------------------------------------------------------------------
__global__ __launch_bounds__(256) void mlp_kernel(
    const float* __restrict__ x, const __bf16* __restrict__ temp,
    float* __restrict__ out, int samp0)
{
    const int n   = samp0 + blockIdx.x;   // global sample index
    const int tid = threadIdx.x;
    const int wv  = tid >> 6;             // 0..3
    const int l   = tid & 63;
    const int pg  = l >> 4;               // 0..3
    const int qg  = l & 15;               // 0..15

    __shared__ float h[128];
    __shared__ float partial[4][128];

    if (tid < 64) ((float2*)h)[tid] = ((const float2*)(x + (size_t)n * 128))[tid];

    const __bf16* row = temp + (size_t)blockIdx.x * TOT;   // chunk-local temp row

    // prefetch layer-0 weights (independent of h)
    bf16x8 w[8];
#pragma unroll
    for (int i = 0; i < 8; ++i)
        w[i] = *(const bf16x8*)(row + 128 + (size_t)(wv * 32 + i * 4 + pg) * 128 + qg * 8);

    int cum = 0;
#pragma unroll
    for (int layer = 0; layer < 3; ++layer) {
        bf16x8 wn2[8];
        if (layer < 2) {
#pragma unroll
            for (int i = 0; i < 8; ++i)
                wn2[i] = *(const bf16x8*)(row + cum + LCHUNK + 128
                        + (size_t)(wv * 32 + i * 4 + pg) * 128 + qg * 8);
        }
        float bv = 0.f;
        if (tid < 128) bv = (float)row[cum + tid];

        float acc[8] = {0, 0, 0, 0, 0, 0, 0, 0};
        __syncthreads();   // h ready
#pragma unroll
        for (int i = 0; i < 8; ++i) {
            float hp = h[wv * 32 + i * 4 + pg];
#pragma unroll
            for (int j = 0; j < 8; ++j) acc[j] += (float)w[i][j] * hp;
        }
#pragma unroll
        for (int j = 0; j < 8; ++j) {
            acc[j] += __shfl_xor(acc[j], 16);
            acc[j] += __shfl_xor(acc[j], 32);
        }
        if (pg == 0) {
#pragma unroll
            for (int j = 0; j < 8; ++j) partial[wv][qg * 8 + j] = acc[j];
        }
        __syncthreads();   // partials ready; everyone done reading h
        if (tid < 128) {
            float v = partial[0][tid] + partial[1][tid] + partial[2][tid] + partial[3][tid]
                    + bv;
            if (layer < 2) v = fmaxf(v, 0.f);
            h[tid] = v;
        }
        if (layer < 2) {
#pragma unroll
            for (int i = 0; i < 8; ++i) w[i] = wn2[i];
        }
        cum += LCHUNK;
    }
    __syncthreads();
    if (tid < 64) ((float2*)(out + (size_t)n * 128))[tid] = ((const float2*)h)[tid];
}

// ---------------------------------------------------------------------------
extern "C" void kernel_launch(void* const* d_in, const int* in_sizes, int n_in,
                              void* d_out, int out_size, void* d_ws, size_t ws_size,
                              hipStream_t stream) {
    const float* int_x = (const float*)d_in[0];  // 4096 x 512
    const float* x     = (const float*)d_in[1];  // 4096 x 128
    const float* W     = (const float*)d_in[2];  // 49536 x 512
    const float* b     = (const float*)d_in[3];  // 49536
    float* out = (float*)d_out;                  // 4096 x 128

    // workspace layout (bf16): A_bf (4 MB) | W_bf (50.7 MB) | temp chunk
    char* ws = (char*)d_ws;
    __bf16* A_bf = (__bf16*)ws;
    size_t offA = (size_t)NSAMP * KDIM * 2;
    __bf16* W_bf = (__bf16*)(ws + offA);
    size_t offW = offA + (size_t)TOT * KDIM * 2;
    __bf16* temp = (__bf16*)(ws + offW);

    // Adaptive chunk: largest of {4096..256} whose temp fits remaining ws.
    // Deterministic given ws_size -> identical work every call (capture-safe).
    // chunk % 256 == 0 (BM=256).
    size_t remain = (ws_size > offW) ? (ws_size - offW) : 0;
    int chunk = 256;
    for (int c = 4096; c >= 256; c >>= 1) {
        if ((size_t)c * TOT * 2 <= remain) { chunk = c; break; }
    }

    int nA4 = NSAMP * KDIM / 4;
    cast_bf16<<<(nA4 + 255) / 256, 256, 0, stream>>>(int_x, A_bf, nA4);
    int nW4 = TOT * KDIM / 4;
    cast_bf16<<<(nW4 + 255) / 256, 256, 0, stream>>>(W, W_bf, nW4);

    for (int samp0 = 0; samp0 < NSAMP; samp0 += chunk) {
        dim3 grid(NUMN, chunk / 256);   // 387 x (chunk/256)
        hyper_gemm<<<grid, 256, 0, stream>>>(A_bf + (size_t)samp0 * KDIM, W_bf, b, temp);
        mlp_kernel<<<chunk, 256, 0, stream>>>(x, temp, out, samp0);
    }
}

// Round 9
// 470.229 us; speedup vs baseline: 2.3227x; 1.0298x over previous
//
#include <hip/hip_runtime.h>
#include <cstdint>
#include <cstddef>

#define NSAMP 4096
#define KDIM  512
#define TOT   49536   // 3 * (128*128 + 128)
#define NUMN  387     // TOT / 128
#define BK    64
#define LCHUNK 16512  // 128 + 128*128, per-layer temp stride

typedef __attribute__((ext_vector_type(8))) __bf16 bf16x8;
typedef __attribute__((ext_vector_type(4))) __bf16 bf16x4;
typedef __attribute__((ext_vector_type(4))) float  f32x4;
typedef __attribute__((ext_vector_type(16))) float f32x16;

#define AS1 __attribute__((address_space(1)))
#define AS3 __attribute__((address_space(3)))

// ---------------------------------------------------------------------------
// fp32 -> bf16 cast, 4 elements per thread (float4 read, 8B write)
// ---------------------------------------------------------------------------
__global__ void cast_bf16(const float* __restrict__ in, __bf16* __restrict__ out, int n4) {
    int i = blockIdx.x * blockDim.x + threadIdx.x;
    int stride = gridDim.x * blockDim.x;
    for (; i < n4; i += stride) {
        float4 v = ((const float4*)in)[i];
        bf16x4 o = { (__bf16)v.x, (__bf16)v.y, (__bf16)v.z, (__bf16)v.w };
        ((bf16x4*)out)[i] = o;
    }
}

// ---------------------------------------------------------------------------
// Hypernetwork GEMM: C[m][n] = sum_k A[m][k]*B[n][k] + bias[n]
// R14 = R13 (BM=256 x BN=128, 4 waves, single-buffer 48KB, 2-barrier loop,
// 2 blocks/CU — best measured: 154us, 680 TF) + two issue-efficiency changes:
//  1. kt loop FULLY UNROLLED: all global_load_lds srcs get kt*128B immediate
//     offsets, all ds_reads get mi*4096B immediates off 4 hoisted xor-granule
//     bases -> per-kt address VALU eliminated (VALUBusy was 18%).
//  2. mfma 16x16x32 -> 32x32x16: same math in HALF the instructions at the
//     higher ubench rate (2382 vs 2075 TF, -17% MFMA-pipe time); C-writes
//     become 64B-contiguous per lane-half (was 32B). C/D mapping per
//     verified m74/m101: col=lane&31, row=(reg&3)+8*(reg>>2)+4*(lane>>5).
// Bank-conflict safety: same property that measured 0 conflicts in R13 —
// every aligned 8-lane group has distinct lane&7 -> distinct xor'd granule
// -> distinct 4-bank sets per LDS phase.
// ---------------------------------------------------------------------------
__global__ __launch_bounds__(256, 2) void hyper_gemm(
    const __bf16* __restrict__ A, const __bf16* __restrict__ B,
    const float* __restrict__ bias, __bf16* __restrict__ C)
{
    __shared__ __bf16 As[256 * BK];   // 32 KB
    __shared__ __bf16 Bs[128 * BK];   // 16 KB

    const int tid  = threadIdx.x;
    const int lane = tid & 63;
    const int l31  = lane & 31;       // mfma row/col index
    const int lhi  = lane >> 5;       // 0..1 k-half
    const int lk   = lane & 7;        // xor-swizzle key (= row&7 for reads)
    const int wv   = tid >> 6;        // 0..3
    const int wm   = wv >> 1;         // 0..1 -> 128 output rows each
    const int wn   = wv & 1;          // 0..1 -> 64 output cols each

    // ---- XCD-congruent swizzle: same-n_t blocks -> same XCD, adjacent ids
    const int num_m = gridDim.y;                    // chunk/256
    const int id    = blockIdx.y * NUMN + blockIdx.x;
    const int gsz   = 8 * num_m;                    // supergroup block count
    const int s     = id / gsz;
    const int r     = id % gsz;
    const int base  = s * 8;
    int w = NUMN - base; if (w > 8) w = 8;          // partial last group (387%8=3)
    const int n_t = base + r % w;
    const int m_t = r / w;

    const int m0 = m_t * 256;   // chunk-local row
    const int n0 = n_t * 128;

    f32x16 acc[4][2] = {};      // [mi 32-row][nj 32-col] per-wave 128x64

    // ---- per-thread staging geometry (k-invariant, hoisted; verbatim R13)
    const __bf16* gAp[8];
    const __bf16* gBp[4];
    int ldsAOff[8], ldsBOff[4];
#pragma unroll
    for (int c = 0; c < 8; ++c) {
        int idx  = c * 256 + tid;           // 0..2047
        int row  = idx >> 3;                // 0..255
        int gsrc = (idx & 7) ^ (row & 7);
        gAp[c] = A + (size_t)(m0 + row) * KDIM + gsrc * 8;
        ldsAOff[c] = idx * 8;
    }
#pragma unroll
    for (int c = 0; c < 4; ++c) {
        int idx  = c * 256 + tid;           // 0..1023
        int row  = idx >> 3;                // 0..127
        int gsrc = (idx & 7) ^ (row & 7);
        gBp[c] = B + (size_t)(n0 + row) * KDIM + gsrc * 8;
        ldsBOff[c] = idx * 8;
    }

    // ---- hoisted read bases: for sub-k step ks, lane reads global granule
    // ks*2+lhi -> LDS granule (ks*2+lhi)^lk. 4 bases each for A/B; mi/nj
    // selected by immediate offset (mi*4096B / nj*4096B) in the ds_read.
    const __bf16* aB[4];
    const __bf16* bB[4];
#pragma unroll
    for (int ks = 0; ks < 4; ++ks) {
        int g = (ks * 2 + lhi) ^ lk;
        aB[ks] = As + (wm * 128 + l31) * BK + g * 8;
        bB[ks] = Bs + (wn * 64  + l31) * BK + g * 8;
    }

#pragma unroll
    for (int kt = 0; kt < KDIM / BK; ++kt) {
        // stage tile kt (single buffer; offsets fold to immediates)
#pragma unroll
        for (int c = 0; c < 8; ++c)
            __builtin_amdgcn_global_load_lds((AS1 void*)(gAp[c] + kt * BK),
                (AS3 void*)(As + ldsAOff[c]), 16, 0, 0);
#pragma unroll
        for (int c = 0; c < 4; ++c)
            __builtin_amdgcn_global_load_lds((AS1 void*)(gBp[c] + kt * BK),
                (AS3 void*)(Bs + ldsBOff[c]), 16, 0, 0);
        __syncthreads();

        // 4 sub-k steps x 8 mfma_32x32x16 = full 64-k tile
#pragma unroll
        for (int ks = 0; ks < 4; ++ks) {
            bf16x8 a0 = *(const bf16x8*)(aB[ks] + 0 * 32 * BK);
            bf16x8 a1 = *(const bf16x8*)(aB[ks] + 1 * 32 * BK);
            bf16x8 a2 = *(const bf16x8*)(aB[ks] + 2 * 32 * BK);
            bf16x8 a3 = *(const bf16x8*)(aB[ks] + 3 * 32 * BK);
            bf16x8 b0 = *(const bf16x8*)(bB[ks] + 0 * 32 * BK);
            bf16x8 b1 = *(const bf16x8*)(bB[ks] + 1 * 32 * BK);
            acc[0][0] = __builtin_amdgcn_mfma_f32_32x32x16_bf16(a0, b0, acc[0][0], 0, 0, 0);
            acc[0][1] = __builtin_amdgcn_mfma_f32_32x32x16_bf16(a0, b1, acc[0][1], 0, 0, 0);
            acc[1][0] = __builtin_amdgcn_mfma_f32_32x32x16_bf16(a1, b0, acc[1][0], 0, 0, 0);
            acc[1][1] = __builtin_amdgcn_mfma_f32_32x32x16_bf16(a1, b1, acc[1][1], 0, 0, 0);
            acc[2][0] = __builtin_amdgcn_mfma_f32_32x32x16_bf16(a2, b0, acc[2][0], 0, 0, 0);
            acc[2][1] = __builtin_amdgcn_mfma_f32_32x32x16_bf16(a2, b1, acc[2][1], 0, 0, 0);
            acc[3][0] = __builtin_amdgcn_mfma_f32_32x32x16_bf16(a3, b0, acc[3][0], 0, 0, 0);
            acc[3][1] = __builtin_amdgcn_mfma_f32_32x32x16_bf16(a3, b1, acc[3][1], 0, 0, 0);
        }
        __syncthreads();
    }

    // --- epilogue: 32x32 C/D layout col=lane&31, row=(reg&3)+8*(reg>>2)
    // +4*(lane>>5) [m74/m101-verified]. Lanes 0..31 write 32 consecutive n
    // at one m (64B segment); lanes 32..63 the m+4 row. Fuse bias, cast bf16.
#pragma unroll
    for (int nj = 0; nj < 2; ++nj) {
        int n = n0 + wn * 64 + nj * 32 + l31;
        float bv = bias[n];
#pragma unroll
        for (int mi = 0; mi < 4; ++mi) {
#pragma unroll
            for (int rr = 0; rr < 16; ++rr) {
                int m = m0 + wm * 128 + mi * 32 + (rr & 3) + 8 * (rr >> 2) + 4 * lhi;
                C[(size_t)m * TOT + n] = (__bf16)(acc[mi][nj][rr] + bv);
            }
        }
    }
}

// ---------------------------------------------------------------------------
// Stage 2: per-sample 3-layer MLP with hypernetwork weights from temp chunk.
// Unchanged (T14 cross-layer weight prefetch; bias hoisted). TOT row stride.
// ---------------------------------------------------------------------------
__global__ __launch_bounds__(256) void mlp_kernel(
    const float* __restrict__ x, const __bf16* __restrict__ temp,
    float* __restrict__ out, int samp0)
{
    const int n   = samp0 + blockIdx.x;   // global sample index
    const int tid = threadIdx.x;
    const int wv  = tid >> 6;             // 0..3
    const int l   = tid & 63;
    const int pg  = l >> 4;               // 0..3
    const int qg  = l & 15;               // 0..15

    __shared__ float h[128];
    __shared__ float partial[4][128];

    if (tid < 64) ((float2*)h)[tid] = ((const float2*)(x + (size_t)n * 128))[tid];

    const __bf16* row = temp + (size_t)blockIdx.x * TOT;   // chunk-local temp row

    // prefetch layer-0 weights (independent of h)
    bf16x8 w[8];
#pragma unroll
    for (int i = 0; i < 8; ++i)
        w[i] = *(const bf16x8*)(row + 128 + (size_t)(wv * 32 + i * 4 + pg) * 128 + qg * 8);

    int cum = 0;
#pragma unroll
    for (int layer = 0; layer < 3; ++layer) {
        bf16x8 wn2[8];
        if (layer < 2) {
#pragma unroll
            for (int i = 0; i < 8; ++i)
                wn2[i] = *(const bf16x8*)(row + cum + LCHUNK + 128
                        + (size_t)(wv * 32 + i * 4 + pg) * 128 + qg * 8);
        }
        float bv = 0.f;
        if (tid < 128) bv = (float)row[cum + tid];

        float acc[8] = {0, 0, 0, 0, 0, 0, 0, 0};
        __syncthreads();   // h ready
#pragma unroll
        for (int i = 0; i < 8; ++i) {
            float hp = h[wv * 32 + i * 4 + pg];
#pragma unroll
            for (int j = 0; j < 8; ++j) acc[j] += (float)w[i][j] * hp;
        }
#pragma unroll
        for (int j = 0; j < 8; ++j) {
            acc[j] += __shfl_xor(acc[j], 16);
            acc[j] += __shfl_xor(acc[j], 32);
        }
        if (pg == 0) {
#pragma unroll
            for (int j = 0; j < 8; ++j) partial[wv][qg * 8 + j] = acc[j];
        }
        __syncthreads();   // partials ready; everyone done reading h
        if (tid < 128) {
            float v = partial[0][tid] + partial[1][tid] + partial[2][tid] + partial[3][tid]
                    + bv;
            if (layer < 2) v = fmaxf(v, 0.f);
            h[tid] = v;
        }
        if (layer < 2) {
#pragma unroll
            for (int i = 0; i < 8; ++i) w[i] = wn2[i];
        }
        cum += LCHUNK;
    }
    __syncthreads();
    if (tid < 64) ((float2*)(out + (size_t)n * 128))[tid] = ((const float2*)h)[tid];
}

// ---------------------------------------------------------------------------
extern "C" void kernel_launch(void* const* d_in, const int* in_sizes, int n_in,
                              void* d_out, int out_size, void* d_ws, size_t ws_size,
                              hipStream_t stream) {
    const float* int_x = (const float*)d_in[0];  // 4096 x 512
    const float* x     = (const float*)d_in[1];  // 4096 x 128
    const float* W     = (const float*)d_in[2];  // 49536 x 512
    const float* b     = (const float*)d_in[3];  // 49536
    float* out = (float*)d_out;                  // 4096 x 128

    // workspace layout (bf16): A_bf (4 MB) | W_bf (50.7 MB) | temp chunk
    char* ws = (char*)d_ws;
    __bf16* A_bf = (__bf16*)ws;
    size_t offA = (size_t)NSAMP * KDIM * 2;
    __bf16* W_bf = (__bf16*)(ws + offA);
    size_t offW = offA + (size_t)TOT * KDIM * 2;
    __bf16* temp = (__bf16*)(ws + offW);

    // Adaptive chunk: largest of {4096..256} whose temp fits remaining ws.
    // Deterministic given ws_size -> identical work every call (capture-safe).
    // chunk % 256 == 0 (BM=256).
    size_t remain = (ws_size > offW) ? (ws_size - offW) : 0;
    int chunk = 256;
    for (int c = 4096; c >= 256; c >>= 1) {
        if ((size_t)c * TOT * 2 <= remain) { chunk = c; break; }
    }

    int nA4 = NSAMP * KDIM / 4;
    cast_bf16<<<(nA4 + 255) / 256, 256, 0, stream>>>(int_x, A_bf, nA4);
    int nW4 = TOT * KDIM / 4;
    cast_bf16<<<(nW4 + 255) / 256, 256, 0, stream>>>(W, W_bf, nW4);

    for (int samp0 = 0; samp0 < NSAMP; samp0 += chunk) {
        dim3 grid(NUMN, chunk / 256);   // 387 x (chunk/256)
        hyper_gemm<<<grid, 256, 0, stream>>>(A_bf + (size_t)samp0 * KDIM, W_bf, b, temp);
        mlp_kernel<<<chunk, 256, 0, stream>>>(x, temp, out, samp0);
    }
}